// Round 1
// 1252.862 us; speedup vs baseline: 1.4170x; 1.4170x over previous
//
#include <hip/hip_runtime.h>
#include <hip/hip_bf16.h>
#include <math.h>

// B=2, N=4096, C=1024, HEADS=16, DH=64, BUCKET=64, N_HASHES=4, n_buckets=64
// BH=32, T=4096, 256 bins (r*64+b), 256 chunks of 64 slots per bh.
//
// NUMERICS CONTRACT (round 5 pass): the discrete path — qk projection and
// bucket rotation — must be an ascending-k fp32 FMA chain per output element
// (replicates the numpy fp32 reference's argmax decisions). sgemm128 below
// preserves that chain bit-for-bit (explicit fmaf, k0 ascending, kk ascending).
// bucket32 is byte-identical to round 5.
//
// SORT (this round): the bitonic sort (510us @ 1.5% occupancy, 29% of total)
// is replaced by a stable LDS counting sort. Keys are bin*4096+token with
// bin = r*64 + bi; the 4 r-segments have disjoint, ordered bin ranges, so the
// global sort == concat of per-(bh,r) sorts. Keys are unique, so "stable
// counting sort by bi, ties by index(=token)" reproduces the bitonic output
// bit-for-bit. Grid 128 = 32 bh * 4 r; ~16KB in / ~16KB out per block.

// ---------------------------------------------------------------------------
// Tiled fp32 GEMM: C[m][n] = seqFMA_k A[m][k]*W[n][k] (+bias at end).
// headLayout=1 -> head layout (qk, v); 0 -> row-major (out).
// ---------------------------------------------------------------------------
__global__ __launch_bounds__(256) void sgemm128(const float* __restrict__ A,
                                                const float* __restrict__ W,
                                                float* __restrict__ out,
                                                int headLayout,
                                                const float* __restrict__ bias) {
    __shared__ float As[8][128];
    __shared__ float Bs[8][128];
    int tid = threadIdx.x;
    int tx = tid & 15, ty = tid >> 4;
    int m0 = blockIdx.x * 128, n0 = blockIdx.y * 128;
    int lr = tid >> 1;
    int lk = (tid & 1) * 4;
    float acc[8][8];
#pragma unroll
    for (int i = 0; i < 8; ++i)
#pragma unroll
        for (int j = 0; j < 8; ++j) acc[i][j] = 0.f;

    for (int k0 = 0; k0 < 1024; k0 += 8) {
        float4 av = *(const float4*)&A[(size_t)(m0 + lr) * 1024 + k0 + lk];
        float4 bv = *(const float4*)&W[(size_t)(n0 + lr) * 1024 + k0 + lk];
        __syncthreads();
        As[lk + 0][lr] = av.x; As[lk + 1][lr] = av.y;
        As[lk + 2][lr] = av.z; As[lk + 3][lr] = av.w;
        Bs[lk + 0][lr] = bv.x; Bs[lk + 1][lr] = bv.y;
        Bs[lk + 2][lr] = bv.z; Bs[lk + 3][lr] = bv.w;
        __syncthreads();
#pragma unroll
        for (int kk = 0; kk < 8; ++kk) {
            float a[8], b[8];
            *(float4*)&a[0] = *(const float4*)&As[kk][tx * 8];
            *(float4*)&a[4] = *(const float4*)&As[kk][tx * 8 + 4];
            *(float4*)&b[0] = *(const float4*)&Bs[kk][ty * 8];
            *(float4*)&b[4] = *(const float4*)&Bs[kk][ty * 8 + 4];
#pragma unroll
            for (int i = 0; i < 8; ++i)
#pragma unroll
                for (int j = 0; j < 8; ++j)
                    acc[i][j] = fmaf(a[i], b[j], acc[i][j]);
        }
    }
#pragma unroll
    for (int i = 0; i < 8; ++i) {
        int m = m0 + tx * 8 + i;
        int bb = m >> 12, t = m & 4095;
#pragma unroll
        for (int j = 0; j < 8; ++j) {
            int n = n0 + ty * 8 + j;
            float val = acc[i][j];
            if (bias) val += bias[n];
            if (headLayout) {
                out[(((size_t)(bb * 16 + (n >> 6))) * 4096 + t) * 64 + (n & 63)] = val;
            } else {
                out[(size_t)m * 1024 + n] = val;
            }
        }
    }
}

// ---------------------------------------------------------------------------
// Bucketing (byte-identical to round 5): one thread per (bh, r, token).
// ---------------------------------------------------------------------------
__global__ __launch_bounds__(256) void bucket32(const float* __restrict__ qk,
                                                const float* __restrict__ rot,
                                                int* __restrict__ keys) {
    int gid = blockIdx.x * 256 + threadIdx.x;   // 0..524287
    int token = gid & 4095;
    int r = (gid >> 12) & 3;
    int bh = gid >> 14;
    const float* q = &qk[((size_t)bh * 4096 + token) * 64];
    float racc[32];
#pragma unroll
    for (int i = 0; i < 32; ++i) racc[i] = 0.f;
    for (int f = 0; f < 64; ++f) {
        float qv = q[f];
        const float* rp = &rot[f * 128 + r * 32];
#pragma unroll
        for (int i = 0; i < 32; ++i) racc[i] = fmaf(qv, rp[i], racc[i]);
    }
    float best = -INFINITY;
    int bi = 0;
#pragma unroll
    for (int i = 0; i < 32; ++i) { if (racc[i] > best) { best = racc[i]; bi = i; } }
#pragma unroll
    for (int i = 0; i < 32; ++i) { float x = -racc[i]; if (x > best) { best = x; bi = 32 + i; } }
    int bin = r * 64 + bi;
    keys[(size_t)bh * 16384 + r * 4096 + token] = bin * 4096 + token;
}

// ---------------------------------------------------------------------------
// Stable counting sort per (bh, r) segment: 4096 keys -> 64 bins, ties by
// token (== storage index). Output bit-identical to the former bitonic sort.
// Grid 128 = 32 bh * 4 r. Block 256; each thread owns a contiguous chunk of
// 16 elements (in-order walk => stability).
// ---------------------------------------------------------------------------
#define PST 257  // u16 row stride for pre[] (odd => spreads LDS banks)

__global__ __launch_bounds__(256) void countsort_kernel(const int* __restrict__ keys,
                                                        int* __restrict__ st_sorted) {
    __shared__ unsigned short pre[64 * PST];  // [bin][thread] counts -> excl. prefix
    __shared__ unsigned char sbin[4096];      // bin of each local element
    __shared__ unsigned short sperm[4096];    // sorted token (local index)
    __shared__ int qsum[64 * 4];              // per-(bin,quarter) sums
    __shared__ int qoff[64 * 4];              // per-(bin,quarter) excl. offsets
    __shared__ int binOffset[64];             // excl. prefix of bin totals

    int tid = threadIdx.x;
    int bh = blockIdx.x >> 2;
    int r = blockIdx.x & 3;
    const int* kb = &keys[(((size_t)bh * 4 + r) << 12)];

    for (int u = tid; u < 64 * PST; u += 256) pre[u] = 0;
    __syncthreads();

    // phase 1: load 16 keys, record bins, count into this thread's column
    int base = tid << 4;
#pragma unroll
    for (int u = 0; u < 4; ++u) {
        int4 kv = *(const int4*)&kb[base + u * 4];
        int b0 = (kv.x >> 12) & 63;
        int b1 = (kv.y >> 12) & 63;
        int b2 = (kv.z >> 12) & 63;
        int b3 = (kv.w >> 12) & 63;
        sbin[base + u * 4 + 0] = (unsigned char)b0;
        sbin[base + u * 4 + 1] = (unsigned char)b1;
        sbin[base + u * 4 + 2] = (unsigned char)b2;
        sbin[base + u * 4 + 3] = (unsigned char)b3;
        pre[b0 * PST + tid]++;
        pre[b1 * PST + tid]++;
        pre[b2 * PST + tid]++;
        pre[b3 * PST + tid]++;
    }
    __syncthreads();

    // phase 2a: quarter sums — thread (b, q) sums its 64-thread span of bin b
    int b = tid & 63, q = tid >> 6;
    {
        int run = 0;
        for (int i = 0; i < 64; ++i) run += pre[b * PST + q * 64 + i];
        qsum[b * 4 + q] = run;
    }
    __syncthreads();

    // phase 2b: per-bin scan over quarters; bin totals into binOffset (temp)
    if (tid < 64) {
        int s0 = qsum[tid * 4 + 0], s1 = qsum[tid * 4 + 1];
        int s2 = qsum[tid * 4 + 2], s3 = qsum[tid * 4 + 3];
        qoff[tid * 4 + 0] = 0;
        qoff[tid * 4 + 1] = s0;
        qoff[tid * 4 + 2] = s0 + s1;
        qoff[tid * 4 + 3] = s0 + s1 + s2;
        binOffset[tid] = s0 + s1 + s2 + s3;   // total for now
    }
    __syncthreads();
    if (tid == 0) {
        int running = 0;
        for (int i = 0; i < 64; ++i) {
            int t = binOffset[i];
            binOffset[i] = running;
            running += t;
        }
    }
    __syncthreads();

    // phase 2c: in-place exclusive prefix within each (bin, quarter) span
    {
        int run2 = qoff[b * 4 + q];
        for (int i = 0; i < 64; ++i) {
            int idx = b * PST + q * 64 + i;
            int t = pre[idx];
            pre[idx] = (unsigned short)run2;
            run2 += t;
        }
    }
    __syncthreads();

    // phase 3: stable scatter — in-index-order walk of this thread's chunk
#pragma unroll
    for (int k = 0; k < 16; ++k) {
        int bin = sbin[base + k];
        int off = pre[bin * PST + tid]++;
        sperm[binOffset[bin] + off] = (unsigned short)(base + k);
    }
    __syncthreads();

    // phase 4: coalesced write of sorted tokens
    int* ob = &st_sorted[(((size_t)bh * 4 + r) << 12)];
#pragma unroll
    for (int u = 0; u < 16; ++u) ob[u * 256 + tid] = (int)sperm[u * 256 + tid];
}

// ---------------------------------------------------------------------------
// Tiled chunked attention (r1 structure; exonerated by r3 bisect).
// ---------------------------------------------------------------------------
__global__ __launch_bounds__(256) void attn_kernel(const float* __restrict__ qk,
                                                   const float* __restrict__ v,
                                                   const int* __restrict__ st_sorted,
                                                   float* __restrict__ o4,
                                                   float* __restrict__ lse4) {
    __shared__ float bufA[128 * 68];  // phase1: kqt[f][row] stride 132; phase2: pT[j][i] stride 68
    __shared__ float vsl[128 * 68];   // [row][c] stride 68
    __shared__ float red[64 * 17];
    __shared__ int posl[128];
    __shared__ float invl[128];

    int tid = threadIdx.x;
    int bh = blockIdx.x >> 8;
    int c = blockIdx.x & 255;
    int r = c >> 6;
    int pc = (c + 255) & 255;
    const int* stb = &st_sorted[(size_t)bh * 16384];
    if (tid < 64) posl[tid] = stb[c * 64 + tid];
    else if (tid < 128) posl[tid] = stb[pc * 64 + (tid - 64)];
    __syncthreads();

    float* kqt = bufA;
    for (int u = 0; u < 8; ++u) {
        int flat = u * 256 + tid;              // 0..2047 float4 units
        int row = flat >> 4;
        int f4 = (flat & 15) * 4;
        size_t gbase = ((size_t)bh * 4096 + posl[row]) * 64 + f4;
        float4 qv = *(const float4*)&qk[gbase];
        kqt[(f4 + 0) * 132 + row] = qv.x;
        kqt[(f4 + 1) * 132 + row] = qv.y;
        kqt[(f4 + 2) * 132 + row] = qv.z;
        kqt[(f4 + 3) * 132 + row] = qv.w;
        *(float4*)&vsl[row * 68 + f4] = *(const float4*)&v[gbase];
    }
    __syncthreads();

    if (tid < 128) {
        float ss = 0.f;
        for (int f = 0; f < 64; ++f) { float x = kqt[f * 132 + tid]; ss += x * x; }
        invl[tid] = 1.0f / fmaxf(sqrtf(ss), 1e-12f);
    }
    __syncthreads();

    int tx = tid & 15, ty = tid >> 4;   // rows i=tx*4..+4 (queries), cols j=ty*8..+8 (keys)
    float acc[4][8];
#pragma unroll
    for (int i = 0; i < 4; ++i)
#pragma unroll
        for (int j = 0; j < 8; ++j) acc[i][j] = 0.f;
    for (int f = 0; f < 64; ++f) {
        float a[4], b[8];
        *(float4*)a = *(const float4*)&kqt[f * 132 + tx * 4];
        *(float4*)&b[0] = *(const float4*)&kqt[f * 132 + ty * 8];
        *(float4*)&b[4] = *(const float4*)&kqt[f * 132 + ty * 8 + 4];
#pragma unroll
        for (int i = 0; i < 4; ++i)
#pragma unroll
            for (int j = 0; j < 8; ++j) acc[i][j] = fmaf(a[i], b[j], acc[i][j]);
    }

    // scale + self-mask
    int qp[4];
#pragma unroll
    for (int ii = 0; ii < 4; ++ii) qp[ii] = posl[tx * 4 + ii];
#pragma unroll
    for (int jj = 0; jj < 8; ++jj) {
        int j = ty * 8 + jj;
        float sc = invl[j] * 0.125f;
        int kp = posl[j];
#pragma unroll
        for (int ii = 0; ii < 4; ++ii) {
            float x = acc[ii][jj] * sc;
            acc[ii][jj] = (qp[ii] == kp) ? -5e4f : x;
        }
    }

    // row max across the 16 ty-groups
#pragma unroll
    for (int ii = 0; ii < 4; ++ii) {
        float pm = acc[ii][0];
#pragma unroll
        for (int jj = 1; jj < 8; ++jj) pm = fmaxf(pm, acc[ii][jj]);
        red[(tx * 4 + ii) * 17 + ty] = pm;
    }
    __syncthreads();
    float m[4];
#pragma unroll
    for (int ii = 0; ii < 4; ++ii) {
        float mm = red[(tx * 4 + ii) * 17 + 0];
        for (int t = 1; t < 16; ++t) mm = fmaxf(mm, red[(tx * 4 + ii) * 17 + t]);
        m[ii] = mm;
    }
    __syncthreads();  // all max reads done before red reuse + all kqt reads done before pT overwrite

    // exp, store transposed probs (unnormalized), partial sums
    float* pT = bufA;
    float ps[4] = {0.f, 0.f, 0.f, 0.f};
#pragma unroll
    for (int jj = 0; jj < 8; ++jj) {
        int j = ty * 8 + jj;
#pragma unroll
        for (int ii = 0; ii < 4; ++ii) {
            float e = __expf(acc[ii][jj] - m[ii]);
            pT[j * 68 + tx * 4 + ii] = e;
            ps[ii] += e;
        }
    }
#pragma unroll
    for (int ii = 0; ii < 4; ++ii) red[(tx * 4 + ii) * 17 + ty] = ps[ii];
    __syncthreads();
    float l[4];
#pragma unroll
    for (int ii = 0; ii < 4; ++ii) {
        float s = 0.f;
        for (int t = 0; t < 16; ++t) s += red[(tx * 4 + ii) * 17 + t];
        l[ii] = s;
    }

    if (ty == 0) {
#pragma unroll
        for (int ii = 0; ii < 4; ++ii) {
            int i = tx * 4 + ii;
            lse4[((size_t)bh * 4 + r) * 4096 + posl[i]] = m[ii] + __logf(l[ii]);
        }
    }

    // PV: rows i=tx*4..+4, cols c=ty*4..+4, K=128
    float acc2[4][4];
#pragma unroll
    for (int i = 0; i < 4; ++i)
#pragma unroll
        for (int j = 0; j < 4; ++j) acc2[i][j] = 0.f;
    for (int j = 0; j < 128; ++j) {
        float a[4], b[4];
        *(float4*)a = *(const float4*)&pT[j * 68 + tx * 4];
        *(float4*)b = *(const float4*)&vsl[j * 68 + ty * 4];
#pragma unroll
        for (int ii = 0; ii < 4; ++ii)
#pragma unroll
            for (int cc = 0; cc < 4; ++cc) acc2[ii][cc] = fmaf(a[ii], b[cc], acc2[ii][cc]);
    }
#pragma unroll
    for (int ii = 0; ii < 4; ++ii) {
        int i = tx * 4 + ii;
        float rl = 1.0f / l[ii];
        size_t ob = (((size_t)bh * 4 + r) * 4096 + posl[i]) * 64 + ty * 4;
        float4 ov;
        ov.x = acc2[ii][0] * rl;
        ov.y = acc2[ii][1] * rl;
        ov.z = acc2[ii][2] * rl;
        ov.w = acc2[ii][3] * rl;
        *(float4*)&o4[ob] = ov;
    }
}

// ---------------------------------------------------------------------------
// Combine hash rounds (softmax over per-round lse). Grid 32768.
// ---------------------------------------------------------------------------
__global__ __launch_bounds__(256) void combine_kernel(const float* __restrict__ o4,
                                                      const float* __restrict__ lse4,
                                                      float* __restrict__ o_bt) {
    int tid = threadIdx.x;
    int gt = blockIdx.x * 4 + (tid >> 6);  // global token 0..131071
    int d = tid & 63;
    int bh = gt >> 12, p = gt & 4095;
    size_t base = ((size_t)bh * 4) * 4096 + p;
    float l0 = lse4[base];
    float l1 = lse4[base + 4096];
    float l2 = lse4[base + 8192];
    float l3 = lse4[base + 12288];
    float mm = fmaxf(fmaxf(l0, l1), fmaxf(l2, l3));
    float w0 = __expf(l0 - mm), w1 = __expf(l1 - mm);
    float w2 = __expf(l2 - mm), w3 = __expf(l3 - mm);
    float W = w0 + w1 + w2 + w3;
    size_t ob = (((size_t)bh * 4) * 4096 + p) * 64 + d;
    const size_t rs = (size_t)4096 * 64;
    float o = w0 * o4[ob]
            + w1 * o4[ob + rs]
            + w2 * o4[ob + 2 * rs]
            + w3 * o4[ob + 3 * rs];
    int b = bh >> 4, h = bh & 15;
    o_bt[((size_t)b * 4096 + p) * 1024 + h * 64 + d] = o / W;
}

// ---------------------------------------------------------------------------
extern "C" void kernel_launch(void* const* d_in, const int* in_sizes, int n_in,
                              void* d_out, int out_size, void* d_ws, size_t ws_size,
                              hipStream_t stream) {
    const float* x    = (const float*)d_in[0];   // queries (2,4096,1024)
    const float* Wqk  = (const float*)d_in[4];   // (1024,1024)
    const float* Wv   = (const float*)d_in[5];
    const float* Wout = (const float*)d_in[6];
    const float* bout = (const float*)d_in[7];   // (1024,)
    const float* rot  = (const float*)d_in[8];   // (64,4,32)
    float* out = (float*)d_out;

    char* ws = (char*)d_ws;
    float* qk32          = (float*)(ws);                        // 33,554,432 B (reused as o_bt)
    float* v             = (float*)(ws + 33554432);             // 33,554,432
    float* o4            = (float*)(ws + 67108864);             // 134,217,728
    float* lse4          = (float*)(ws + 201326592);            // 2,097,152
    int* keys            = (int*)(ws + 203423744);              // 2,097,152
    int* st_sorted       = (int*)(ws + 205520896);              // 2,097,152
    float* o_bt          = qk32;                                // alias: qk32 dead after attn

    sgemm128<<<dim3(64, 8), 256, 0, stream>>>(x, Wqk, qk32, 1, nullptr);
    sgemm128<<<dim3(64, 8), 256, 0, stream>>>(x, Wv, v, 1, nullptr);
    bucket32<<<2048, 256, 0, stream>>>(qk32, rot, keys);
    countsort_kernel<<<128, 256, 0, stream>>>(keys, st_sorted);
    attn_kernel<<<8192, 256, 0, stream>>>(qk32, v, st_sorted, o4, lse4);
    combine_kernel<<<32768, 256, 0, stream>>>(o4, lse4, o_bt);
    sgemm128<<<dim3(64, 8), 256, 0, stream>>>(o_bt, Wout, out, 0, bout);
}

// Round 4
// 1164.816 us; speedup vs baseline: 1.5241x; 1.0756x over previous
//
#include <hip/hip_runtime.h>
#include <hip/hip_bf16.h>
#include <math.h>

// B=2, N=4096, C=1024, HEADS=16, DH=64, BUCKET=64, N_HASHES=4, n_buckets=64
// BH=32, T=4096, 256 bins (r*64+b), 256 chunks of 64 slots per bh.
//
// NUMERICS CONTRACT: the discrete path — qk projection and bucket rotation —
// must be an ascending-k fp32 FMA chain per output element (replicates the
// numpy fp32 reference's argmax decisions). sgemm128 preserves that chain
// bit-for-bit (explicit fmaf, k0 ascending, kk ascending; double-buffering
// only reschedules memory, not arithmetic). attn/PV chains bit-identical to
// round 1 (V words read from global are the same fp32 values vsl held).
//
// ROUND 4: rounds 2/3 died to container failures (pod already sick in round
// 1: 1055s npz push). Audit found no OOB/race/divergent-barrier. Defensive
// change only: sgemm's conditional in-loop __syncthreads() restructured to an
// UNCONDITIONAL barrier (127 pipelined iters + barrier-free epilogue tile) —
// same hazard proof, same FMA chain, boring control flow. attn/bucket32/
// countsort/combine byte-identical to round 2/3.

// ---------------------------------------------------------------------------
// Tiled fp32 GEMM: C[m][n] = seqFMA_k A[m][k]*W[n][k] (+bias at end).
// headLayout=1 -> head layout (qk, v); 0 -> row-major (out).
// 128x128 tile, BK=8, 256 threads, 8x8 micro-tile, double-buffered LDS.
// Grid: 512 1-D blocks; swz maps each XCD (id%8) to one contiguous n-panel.
// ---------------------------------------------------------------------------
#define SG_COMPUTE(BUF)                                                      \
    {                                                                        \
        _Pragma("unroll")                                                    \
        for (int kk = 0; kk < 8; ++kk) {                                     \
            float a[8], b[8];                                                \
            *(float4*)&a[0] = *(const float4*)&As[BUF][kk][tx * 8];          \
            *(float4*)&a[4] = *(const float4*)&As[BUF][kk][tx * 8 + 4];      \
            *(float4*)&b[0] = *(const float4*)&Bs[BUF][kk][ty * 8];          \
            *(float4*)&b[4] = *(const float4*)&Bs[BUF][kk][ty * 8 + 4];      \
            _Pragma("unroll")                                                \
            for (int i = 0; i < 8; ++i)                                      \
                _Pragma("unroll")                                            \
                for (int j = 0; j < 8; ++j)                                  \
                    acc[i][j] = fmaf(a[i], b[j], acc[i][j]);                 \
        }                                                                    \
    }

__global__ __launch_bounds__(256) void sgemm128(const float* __restrict__ A,
                                                const float* __restrict__ W,
                                                float* __restrict__ out,
                                                int headLayout,
                                                const float* __restrict__ bias) {
    __shared__ float As[2][8][128];
    __shared__ float Bs[2][8][128];
    int tid = threadIdx.x;
    int tx = tid & 15, ty = tid >> 4;
    int id = blockIdx.x;                      // 0..511
    int swz = (id & 7) * 64 + (id >> 3);      // XCD id%8 -> contiguous chunk
    int m0 = (swz & 63) * 128;                // 64 m-tiles
    int n0 = (swz >> 6) * 128;                // 8 n-tiles (const per XCD chunk)
    int lr = tid >> 1;
    int lk = (tid & 1) * 4;
    const float* pA = &A[(size_t)(m0 + lr) * 1024 + lk];
    const float* pB = &W[(size_t)(n0 + lr) * 1024 + lk];
    float acc[8][8];
#pragma unroll
    for (int i = 0; i < 8; ++i)
#pragma unroll
        for (int j = 0; j < 8; ++j) acc[i][j] = 0.f;

    // prologue: stage tile 0 into buffer 0
    float4 av = *(const float4*)&pA[0];
    float4 bv = *(const float4*)&pB[0];
    As[0][lk + 0][lr] = av.x; As[0][lk + 1][lr] = av.y;
    As[0][lk + 2][lr] = av.z; As[0][lk + 3][lr] = av.w;
    Bs[0][lk + 0][lr] = bv.x; Bs[0][lk + 1][lr] = bv.y;
    Bs[0][lk + 2][lr] = bv.z; Bs[0][lk + 3][lr] = bv.w;
    __syncthreads();

    // 127 pipelined iterations, UNCONDITIONAL barrier each; tile it lives in
    // buffer it&1. Write of buf[nxt] in iter it is safe: buf[nxt] was last
    // READ in iter it-1, sealed by iter it-1's barrier.
    for (int it = 0; it < 127; ++it) {
        int cur = it & 1;
        int nxt = cur ^ 1;
        av = *(const float4*)&pA[(it + 1) * 8];
        bv = *(const float4*)&pB[(it + 1) * 8];
        SG_COMPUTE(cur)
        As[nxt][lk + 0][lr] = av.x; As[nxt][lk + 1][lr] = av.y;
        As[nxt][lk + 2][lr] = av.z; As[nxt][lk + 3][lr] = av.w;
        Bs[nxt][lk + 0][lr] = bv.x; Bs[nxt][lk + 1][lr] = bv.y;
        Bs[nxt][lk + 2][lr] = bv.z; Bs[nxt][lk + 3][lr] = bv.w;
        __syncthreads();
    }
    // epilogue: tile 127 is in buffer 1; no barrier needed after.
    SG_COMPUTE(1)

#pragma unroll
    for (int i = 0; i < 8; ++i) {
        int m = m0 + tx * 8 + i;
        int bb = m >> 12, t = m & 4095;
#pragma unroll
        for (int j = 0; j < 8; ++j) {
            int n = n0 + ty * 8 + j;
            float val = acc[i][j];
            if (bias) val += bias[n];
            if (headLayout) {
                out[(((size_t)(bb * 16 + (n >> 6))) * 4096 + t) * 64 + (n & 63)] = val;
            } else {
                out[(size_t)m * 1024 + n] = val;
            }
        }
    }
}
#undef SG_COMPUTE

// ---------------------------------------------------------------------------
// Bucketing: one thread per (bh, r, token). r/bh derived from blockIdx
// only (wave-uniform rot addresses -> scalar loads); q loads float4.
// FMA chain per racc[i] is f-ascending -> bit-identical to round 5.
// ---------------------------------------------------------------------------
__global__ __launch_bounds__(256) void bucket32(const float* __restrict__ qk,
                                                const float* __restrict__ rot,
                                                int* __restrict__ keys) {
    int tid = threadIdx.x;
    int blk = blockIdx.x;                 // 0..2047
    int token = (blk & 15) * 256 + tid;
    int r = (blk >> 4) & 3;               // block-uniform
    int bh = blk >> 6;                    // block-uniform
    const float* q = &qk[((size_t)bh * 4096 + token) * 64];
    float racc[32];
#pragma unroll
    for (int i = 0; i < 32; ++i) racc[i] = 0.f;
    for (int f0 = 0; f0 < 64; f0 += 4) {
        float4 qv = *(const float4*)&q[f0];
        const float* rp0 = &rot[(f0 + 0) * 128 + r * 32];
        const float* rp1 = rp0 + 128;
        const float* rp2 = rp0 + 256;
        const float* rp3 = rp0 + 384;
#pragma unroll
        for (int i = 0; i < 32; ++i) racc[i] = fmaf(qv.x, rp0[i], racc[i]);
#pragma unroll
        for (int i = 0; i < 32; ++i) racc[i] = fmaf(qv.y, rp1[i], racc[i]);
#pragma unroll
        for (int i = 0; i < 32; ++i) racc[i] = fmaf(qv.z, rp2[i], racc[i]);
#pragma unroll
        for (int i = 0; i < 32; ++i) racc[i] = fmaf(qv.w, rp3[i], racc[i]);
    }
    float best = -INFINITY;
    int bi = 0;
#pragma unroll
    for (int i = 0; i < 32; ++i) { if (racc[i] > best) { best = racc[i]; bi = i; } }
#pragma unroll
    for (int i = 0; i < 32; ++i) { float x = -racc[i]; if (x > best) { best = x; bi = 32 + i; } }
    int bin = r * 64 + bi;
    keys[(size_t)bh * 16384 + r * 4096 + token] = bin * 4096 + token;
}

// ---------------------------------------------------------------------------
// Stable counting sort per (bh, r) segment (unchanged; bit-identical output).
// ---------------------------------------------------------------------------
#define PST 257  // u16 row stride for pre[] (odd => spreads LDS banks)

__global__ __launch_bounds__(256) void countsort_kernel(const int* __restrict__ keys,
                                                        int* __restrict__ st_sorted) {
    __shared__ unsigned short pre[64 * PST];
    __shared__ unsigned char sbin[4096];
    __shared__ unsigned short sperm[4096];
    __shared__ int qsum[64 * 4];
    __shared__ int qoff[64 * 4];
    __shared__ int binOffset[64];

    int tid = threadIdx.x;
    int bh = blockIdx.x >> 2;
    int r = blockIdx.x & 3;
    const int* kb = &keys[(((size_t)bh * 4 + r) << 12)];

    for (int u = tid; u < 64 * PST; u += 256) pre[u] = 0;
    __syncthreads();

    int base = tid << 4;
#pragma unroll
    for (int u = 0; u < 4; ++u) {
        int4 kv = *(const int4*)&kb[base + u * 4];
        int b0 = (kv.x >> 12) & 63;
        int b1 = (kv.y >> 12) & 63;
        int b2 = (kv.z >> 12) & 63;
        int b3 = (kv.w >> 12) & 63;
        sbin[base + u * 4 + 0] = (unsigned char)b0;
        sbin[base + u * 4 + 1] = (unsigned char)b1;
        sbin[base + u * 4 + 2] = (unsigned char)b2;
        sbin[base + u * 4 + 3] = (unsigned char)b3;
        pre[b0 * PST + tid]++;
        pre[b1 * PST + tid]++;
        pre[b2 * PST + tid]++;
        pre[b3 * PST + tid]++;
    }
    __syncthreads();

    int b = tid & 63, q = tid >> 6;
    {
        int run = 0;
        for (int i = 0; i < 64; ++i) run += pre[b * PST + q * 64 + i];
        qsum[b * 4 + q] = run;
    }
    __syncthreads();

    if (tid < 64) {
        int s0 = qsum[tid * 4 + 0], s1 = qsum[tid * 4 + 1];
        int s2 = qsum[tid * 4 + 2], s3 = qsum[tid * 4 + 3];
        qoff[tid * 4 + 0] = 0;
        qoff[tid * 4 + 1] = s0;
        qoff[tid * 4 + 2] = s0 + s1;
        qoff[tid * 4 + 3] = s0 + s1 + s2;
        binOffset[tid] = s0 + s1 + s2 + s3;
    }
    __syncthreads();
    if (tid == 0) {
        int running = 0;
        for (int i = 0; i < 64; ++i) {
            int t = binOffset[i];
            binOffset[i] = running;
            running += t;
        }
    }
    __syncthreads();

    {
        int run2 = qoff[b * 4 + q];
        for (int i = 0; i < 64; ++i) {
            int idx = b * PST + q * 64 + i;
            int t = pre[idx];
            pre[idx] = (unsigned short)run2;
            run2 += t;
        }
    }
    __syncthreads();

#pragma unroll
    for (int k = 0; k < 16; ++k) {
        int bin = sbin[base + k];
        int off = pre[bin * PST + tid]++;
        sperm[binOffset[bin] + off] = (unsigned short)(base + k);
    }
    __syncthreads();

    int* ob = &st_sorted[(((size_t)bh * 4 + r) << 12)];
#pragma unroll
    for (int u = 0; u < 16; ++u) ob[u * 256 + tid] = (int)sperm[u * 256 + tid];
}

// ---------------------------------------------------------------------------
// Tiled chunked attention. Grid 8192 = 32 bh * 256 chunks. Block 256.
// LDS ~40KB -> 4 blocks/CU. kqt XOR-swizzled (write conflicts 8-way -> free).
// V read direct from global in PV (4-deep register prefetch); pT stored as
// float4 (conflict-free). All fp32 FMA chains bit-identical to round 1.
// ---------------------------------------------------------------------------
__global__ __launch_bounds__(256) void attn_kernel(const float* __restrict__ qk,
                                                   const float* __restrict__ v,
                                                   const int* __restrict__ st_sorted,
                                                   float* __restrict__ o4,
                                                   float* __restrict__ lse4) {
    __shared__ float bufA[128 * 68];  // phase1: kqt[f][row^swz] stride 132; phase2: pT[j][i] stride 68
    __shared__ float red[64 * 17];
    __shared__ int posl[128];
    __shared__ float invl[128];

    int tid = threadIdx.x;
    int bh = blockIdx.x >> 8;
    int c = blockIdx.x & 255;
    int r = c >> 6;
    int pc = (c + 255) & 255;
    const int* stb = &st_sorted[(size_t)bh * 16384];
    if (tid < 64) posl[tid] = stb[c * 64 + tid];
    else if (tid < 128) posl[tid] = stb[pc * 64 + (tid - 64)];
    __syncthreads();

    // stage qk -> kqt transposed, XOR-swizzled: row' = row ^ (4*((f>>2)&7)).
    // Write banks: 2-way (free). All reads below apply the same swizzle.
    float* kqt = bufA;
    for (int u = 0; u < 8; ++u) {
        int flat = u * 256 + tid;              // 0..2047 float4 units
        int row = flat >> 4;
        int f4 = (flat & 15) * 4;
        size_t gbase = ((size_t)bh * 4096 + posl[row]) * 64 + f4;
        float4 qv = *(const float4*)&qk[gbase];
        int rw = row ^ ((((f4 >> 2)) & 7) << 2);   // f4>>2 == f>>2 for f in [f4,f4+3]
        kqt[(f4 + 0) * 132 + rw] = qv.x;
        kqt[(f4 + 1) * 132 + rw] = qv.y;
        kqt[(f4 + 2) * 132 + rw] = qv.z;
        kqt[(f4 + 3) * 132 + rw] = qv.w;
    }
    __syncthreads();

    if (tid < 128) {
        float ss = 0.f;
        for (int f = 0; f < 64; ++f) {
            int s = ((f >> 2) & 7) << 2;
            float x = kqt[f * 132 + (tid ^ s)];
            ss += x * x;
        }
        invl[tid] = 1.0f / fmaxf(sqrtf(ss), 1e-12f);
    }
    __syncthreads();

    int tx = tid & 15, ty = tid >> 4;   // rows i=tx*4..+4 (queries), cols j=ty*8..+8 (keys)
    float acc[4][8];
#pragma unroll
    for (int i = 0; i < 4; ++i)
#pragma unroll
        for (int j = 0; j < 8; ++j) acc[i][j] = 0.f;
    for (int f = 0; f < 64; ++f) {
        int s = ((f >> 2) & 7) << 2;
        float a[4], b[8];
        *(float4*)a = *(const float4*)&kqt[f * 132 + ((tx * 4) ^ s)];
        *(float4*)&b[0] = *(const float4*)&kqt[f * 132 + ((ty * 8) ^ s)];
        *(float4*)&b[4] = *(const float4*)&kqt[f * 132 + ((ty * 8 + 4) ^ s)];
#pragma unroll
        for (int i = 0; i < 4; ++i)
#pragma unroll
            for (int j = 0; j < 8; ++j) acc[i][j] = fmaf(a[i], b[j], acc[i][j]);
    }

    // scale + self-mask
    int qp[4];
#pragma unroll
    for (int ii = 0; ii < 4; ++ii) qp[ii] = posl[tx * 4 + ii];
#pragma unroll
    for (int jj = 0; jj < 8; ++jj) {
        int j = ty * 8 + jj;
        float sc = invl[j] * 0.125f;
        int kp = posl[j];
#pragma unroll
        for (int ii = 0; ii < 4; ++ii) {
            float x = acc[ii][jj] * sc;
            acc[ii][jj] = (qp[ii] == kp) ? -5e4f : x;
        }
    }

    // row max across the 16 ty-groups
#pragma unroll
    for (int ii = 0; ii < 4; ++ii) {
        float pm = acc[ii][0];
#pragma unroll
        for (int jj = 1; jj < 8; ++jj) pm = fmaxf(pm, acc[ii][jj]);
        red[(tx * 4 + ii) * 17 + ty] = pm;
    }
    __syncthreads();
    float m[4];
#pragma unroll
    for (int ii = 0; ii < 4; ++ii) {
        float mm = red[(tx * 4 + ii) * 17 + 0];
        for (int t = 1; t < 16; ++t) mm = fmaxf(mm, red[(tx * 4 + ii) * 17 + t]);
        m[ii] = mm;
    }
    __syncthreads();  // max reads done before red reuse + kqt reads done before pT overwrite

    // exp, store transposed probs as float4 (conflict-free), partial sums.
    // ps[ii] chain over jj ascending — identical sequence to round 1.
    float* pT = bufA;
    float ps[4] = {0.f, 0.f, 0.f, 0.f};
#pragma unroll
    for (int jj = 0; jj < 8; ++jj) {
        int j = ty * 8 + jj;
        float e0 = __expf(acc[0][jj] - m[0]);
        float e1 = __expf(acc[1][jj] - m[1]);
        float e2 = __expf(acc[2][jj] - m[2]);
        float e3 = __expf(acc[3][jj] - m[3]);
        ps[0] += e0; ps[1] += e1; ps[2] += e2; ps[3] += e3;
        float4 ev; ev.x = e0; ev.y = e1; ev.z = e2; ev.w = e3;
        *(float4*)&pT[j * 68 + tx * 4] = ev;
    }
#pragma unroll
    for (int ii = 0; ii < 4; ++ii) red[(tx * 4 + ii) * 17 + ty] = ps[ii];
    __syncthreads();
    float l[4];
#pragma unroll
    for (int ii = 0; ii < 4; ++ii) {
        float s = 0.f;
        for (int t = 0; t < 16; ++t) s += red[(tx * 4 + ii) * 17 + t];
        l[ii] = s;
    }

    if (ty == 0) {
#pragma unroll
        for (int ii = 0; ii < 4; ++ii) {
            int i = tx * 4 + ii;
            lse4[((size_t)bh * 4 + r) * 4096 + posl[i]] = m[ii] + __logf(l[ii]);
        }
    }

    // PV: rows i=tx*4..+4, cols c=ty*4..+4, K=128. V direct from global
    // (same fp32 words vsl previously held -> bit-identical accumulation).
    const float* vb = v + (size_t)bh * 4096 * 64 + ty * 4;
    float acc2[4][4];
#pragma unroll
    for (int i = 0; i < 4; ++i)
#pragma unroll
        for (int j = 0; j < 4; ++j) acc2[i][j] = 0.f;

    float4 p0 = *(const float4*)&vb[(size_t)posl[0] * 64];
    float4 p1 = *(const float4*)&vb[(size_t)posl[1] * 64];
    float4 p2 = *(const float4*)&vb[(size_t)posl[2] * 64];
    float4 p3 = *(const float4*)&vb[(size_t)posl[3] * 64];
    for (int j0 = 0; j0 < 128; j0 += 4) {
        float4 c0 = p0, c1 = p1, c2 = p2, c3 = p3;
        if (j0 + 4 < 128) {
            p0 = *(const float4*)&vb[(size_t)posl[j0 + 4] * 64];
            p1 = *(const float4*)&vb[(size_t)posl[j0 + 5] * 64];
            p2 = *(const float4*)&vb[(size_t)posl[j0 + 6] * 64];
            p3 = *(const float4*)&vb[(size_t)posl[j0 + 7] * 64];
        }
#define PVSTEP(JJ, CV)                                                       \
        {                                                                    \
            float a_[4];                                                     \
            *(float4*)a_ = *(const float4*)&pT[(j0 + (JJ)) * 68 + tx * 4];   \
            acc2[0][0] = fmaf(a_[0], CV.x, acc2[0][0]);                      \
            acc2[0][1] = fmaf(a_[0], CV.y, acc2[0][1]);                      \
            acc2[0][2] = fmaf(a_[0], CV.z, acc2[0][2]);                      \
            acc2[0][3] = fmaf(a_[0], CV.w, acc2[0][3]);                      \
            acc2[1][0] = fmaf(a_[1], CV.x, acc2[1][0]);                      \
            acc2[1][1] = fmaf(a_[1], CV.y, acc2[1][1]);                      \
            acc2[1][2] = fmaf(a_[1], CV.z, acc2[1][2]);                      \
            acc2[1][3] = fmaf(a_[1], CV.w, acc2[1][3]);                      \
            acc2[2][0] = fmaf(a_[2], CV.x, acc2[2][0]);                      \
            acc2[2][1] = fmaf(a_[2], CV.y, acc2[2][1]);                      \
            acc2[2][2] = fmaf(a_[2], CV.z, acc2[2][2]);                      \
            acc2[2][3] = fmaf(a_[2], CV.w, acc2[2][3]);                      \
            acc2[3][0] = fmaf(a_[3], CV.x, acc2[3][0]);                      \
            acc2[3][1] = fmaf(a_[3], CV.y, acc2[3][1]);                      \
            acc2[3][2] = fmaf(a_[3], CV.z, acc2[3][2]);                      \
            acc2[3][3] = fmaf(a_[3], CV.w, acc2[3][3]);                      \
        }
        PVSTEP(0, c0)
        PVSTEP(1, c1)
        PVSTEP(2, c2)
        PVSTEP(3, c3)
#undef PVSTEP
    }
#pragma unroll
    for (int ii = 0; ii < 4; ++ii) {
        int i = tx * 4 + ii;
        float rl = 1.0f / l[ii];
        size_t ob = (((size_t)bh * 4 + r) * 4096 + posl[i]) * 64 + ty * 4;
        float4 ov;
        ov.x = acc2[ii][0] * rl;
        ov.y = acc2[ii][1] * rl;
        ov.z = acc2[ii][2] * rl;
        ov.w = acc2[ii][3] * rl;
        *(float4*)&o4[ob] = ov;
    }
}

// ---------------------------------------------------------------------------
// Combine hash rounds (softmax over per-round lse). Grid 32768.
// ---------------------------------------------------------------------------
__global__ __launch_bounds__(256) void combine_kernel(const float* __restrict__ o4,
                                                      const float* __restrict__ lse4,
                                                      float* __restrict__ o_bt) {
    int tid = threadIdx.x;
    int gt = blockIdx.x * 4 + (tid >> 6);  // global token 0..131071
    int d = tid & 63;
    int bh = gt >> 12, p = gt & 4095;
    size_t base = ((size_t)bh * 4) * 4096 + p;
    float l0 = lse4[base];
    float l1 = lse4[base + 4096];
    float l2 = lse4[base + 8192];
    float l3 = lse4[base + 12288];
    float mm = fmaxf(fmaxf(l0, l1), fmaxf(l2, l3));
    float w0 = __expf(l0 - mm), w1 = __expf(l1 - mm);
    float w2 = __expf(l2 - mm), w3 = __expf(l3 - mm);
    float W = w0 + w1 + w2 + w3;
    size_t ob = (((size_t)bh * 4) * 4096 + p) * 64 + d;
    const size_t rs = (size_t)4096 * 64;
    float o = w0 * o4[ob]
            + w1 * o4[ob + rs]
            + w2 * o4[ob + 2 * rs]
            + w3 * o4[ob + 3 * rs];
    int b = bh >> 4, h = bh & 15;
    o_bt[((size_t)b * 4096 + p) * 1024 + h * 64 + d] = o / W;
}

// ---------------------------------------------------------------------------
extern "C" void kernel_launch(void* const* d_in, const int* in_sizes, int n_in,
                              void* d_out, int out_size, void* d_ws, size_t ws_size,
                              hipStream_t stream) {
    const float* x    = (const float*)d_in[0];   // queries (2,4096,1024)
    const float* Wqk  = (const float*)d_in[4];   // (1024,1024)
    const float* Wv   = (const float*)d_in[5];
    const float* Wout = (const float*)d_in[6];
    const float* bout = (const float*)d_in[7];   // (1024,)
    const float* rot  = (const float*)d_in[8];   // (64,4,32)
    float* out = (float*)d_out;

    char* ws = (char*)d_ws;
    float* qk32          = (float*)(ws);                        // 33,554,432 B (reused as o_bt)
    float* v             = (float*)(ws + 33554432);             // 33,554,432
    float* o4            = (float*)(ws + 67108864);             // 134,217,728
    float* lse4          = (float*)(ws + 201326592);            // 2,097,152
    int* keys            = (int*)(ws + 203423744);              // 2,097,152
    int* st_sorted       = (int*)(ws + 205520896);              // 2,097,152
    float* o_bt          = qk32;                                // alias: qk32 dead after attn

    sgemm128<<<512, 256, 0, stream>>>(x, Wqk, qk32, 1, nullptr);
    sgemm128<<<512, 256, 0, stream>>>(x, Wv, v, 1, nullptr);
    bucket32<<<2048, 256, 0, stream>>>(qk32, rot, keys);
    countsort_kernel<<<128, 256, 0, stream>>>(keys, st_sorted);
    attn_kernel<<<8192, 256, 0, stream>>>(qk32, v, st_sorted, o4, lse4);
    combine_kernel<<<32768, 256, 0, stream>>>(o4, lse4, o_bt);
    sgemm128<<<512, 256, 0, stream>>>(o_bt, Wout, out, 0, bout);
}